// Round 10
// baseline (16.425 us; speedup 1.0000x reference)
//
#include <hip/hip_runtime.h>
#include <math.h>
#include <type_traits>

#define NQ     12
#define DIM    4096
#define DEPTH  6
#define NBATCH 256
#define NT     512     // 8 waves per block -> 2 waves per SIMD
#define NREG   8       // state elements per thread

#if defined(__has_builtin)
#  if __has_builtin(__builtin_amdgcn_permlane16_swap) && __has_builtin(__builtin_amdgcn_permlane32_swap)
#    define USE_PERMLANE 1
#  else
#    define USE_PERMLANE 0
#  endif
#else
#  define USE_PERMLANE 0
#endif

// ---------------------------------------------------------------------------
// CNOT-ladder perm = Gray map g(j)=j^(j>>1), linear over GF(2)^12; all perms
// folded into gates: depth-d gate on logical bit b = butterfly on XOR-axis
// V = A^d e_b, sign selector M = row b of A^{-d} (A^16=I):
//   new[j] = x[j] + tau(j)*x[j^V],  tau(j) = parity(M&j) ? +t : -t, t=tan(th/2)
// (tan-normalized; global scale prod(cos) applied once in the observer).
// Storage j = (tid<<3)|r, tid 0..511, r 0..7.
//
// ROUND 10 (R9 passed, 14.4us; latency-chain attack):
// (a) cross3: the three thread-crossing gates b=11,10,9 commute; fuse into
//     ONE 8-term exchange from one LDS snapshot -> 1 barrier/depth (was 2),
//     1 round-trip latency/depth. Cross signs parity(Mj&Vi) are constexpr.
// (b) lane gates all-VALU via __builtin_amdgcn_permlane16/32_swap BUILTINS
//     (distinct SSA results -> no register aliasing, the suspected R6/R8
//     inline-asm failure). Combine r[0]^r[1]^v is convention-independent.
//     Guarded by __has_builtin; fallback = R9-proven swizzle/shfl path.
// DS pipe now carries only cross3 (2 writes + 14 reads /thread/depth).
// ---------------------------------------------------------------------------

__host__ __device__ constexpr unsigned axmask(int d, int b) {
    unsigned m = 1u << b;
    for (int i = 0; i < d; ++i) m = (m ^ (m >> 1)) & 0xFFFu;
    return m;
}
__host__ __device__ constexpr unsigned selmask(int d, int b) {
    unsigned m = 1u << b;
    for (int i = 0; i < 16 - d; ++i) m = (m ^ ((m << 1) & 0xFFFu)) & 0xFFFu;
    return m;
}
__host__ __device__ constexpr int cpopc(unsigned v) {
    int c = 0; while (v) { c += (int)(v & 1u); v >>= 1; } return c;
}

template<int I, int N, class F>
__device__ __forceinline__ void sfor(F&& f) {
    if constexpr (I < N) {
        f(std::integral_constant<int, I>{});
        sfor<I + 1, N>(static_cast<F&&>(f));
    }
}

// ---- cross-lane primitives ----
template<int CTRL>
__device__ __forceinline__ float dppx(float v) {
    int iv = __float_as_int(v);
    return __int_as_float(__builtin_amdgcn_update_dpp(iv, iv, CTRL, 0xF, 0xF, false));
}
template<int M4>
__device__ __forceinline__ float lxor_low(float v) {
    static_assert(M4 >= 1 && M4 <= 15, "low mask");
    if constexpr      (M4 == 1)  return dppx<0xB1>(v);    // quad_perm xor1
    else if constexpr (M4 == 2)  return dppx<0x4E>(v);    // quad_perm xor2
    else if constexpr (M4 == 3)  return dppx<0x1B>(v);    // quad_perm xor3
    else if constexpr (M4 == 7)  return dppx<0x141>(v);   // row_half_mirror
    else if constexpr (M4 == 15) return dppx<0x140>(v);   // row_mirror
    else if constexpr ((M4 & 8) == 0)   // 4,5,6 = 7 ^ {3,2,1}
        return lxor_low<M4 ^ 7>(dppx<0x141>(v));
    else                                // 8..14 = 15 ^ {7..1}
        return lxor_low<M4 ^ 15>(dppx<0x140>(v));
}

#if USE_PERMLANE
typedef unsigned u32x2 __attribute__((ext_vector_type(2)));
__device__ __forceinline__ float plx16(float v) {
    unsigned u = __float_as_uint(v);
    u32x2 r = __builtin_amdgcn_permlane16_swap(u, u, false, false);
    return __uint_as_float(r[0] ^ r[1] ^ u);   // own-term cancels -> partner
}
__device__ __forceinline__ float plx32(float v) {
    unsigned u = __float_as_uint(v);
    u32x2 r = __builtin_amdgcn_permlane32_swap(u, u, false, false);
    return __uint_as_float(r[0] ^ r[1] ^ u);
}
template<int MASK>
__device__ __forceinline__ float lxor(float v) {
    static_assert(MASK > 0 && MASK < 64, "lane mask");
    float r = v;
    if constexpr (MASK & 32) r = plx32(r);
    if constexpr (MASK & 16) r = plx16(r);
    if constexpr (MASK & 15) r = lxor_low<MASK & 15>(r);
    return r;
}
#else
template<int MASK>
__device__ __forceinline__ float lxor(float v) {
    static_assert(MASK > 0 && MASK < 64, "lane mask");
    if constexpr (MASK >= 32) {
        return __shfl_xor(v, MASK, 64);
    } else if constexpr (MASK >= 16) {
        return __int_as_float(__builtin_amdgcn_ds_swizzle(__float_as_int(v),
                                                          (MASK << 10) | 0x1F));
    } else {
        return lxor_low<MASK>(v);
    }
}
#endif

// swizzled LDS word address: thread t, chunk k in 0..1, 8 floats/thread
__device__ __forceinline__ int lad(int t, int k) {
    return t * 8 + 4 * (k ^ ((t >> 2) & 1));
}

// ---- pure-register gate (b<=2), tan form: 1 fma/elem ----
template<int D, int B>
__device__ __forceinline__ void gate_reg(float (&st)[NREG], int tid, float t) {
    constexpr unsigned V = axmask(D, B), M = selmask(D, B);
    static_assert((V >> 3) == 0 && V != 0, "reg gate");
    constexpr int VR = (int)V;
    constexpr unsigned MR = M & 7u, MT = M >> 3;
    const float tp = (__popc(MT & (unsigned)tid) & 1) ? t : -t;
    const float tn = -tp;
    sfor<0, NREG>([&](auto RC) {
        constexpr int r = RC.value, r2 = r ^ VR;
        if constexpr (r2 > r) {
            constexpr bool p0 = (cpopc(MR & (unsigned)r)  & 1) != 0;
            constexpr bool p1 = (cpopc(MR & (unsigned)r2) & 1) != 0;
            float a0 = st[r];
            st[r]  = fmaf(p0 ? tn : tp, st[r2], st[r]);
            st[r2] = fmaf(p1 ? tn : tp, a0,     st[r2]);
        }
    });
}

// ---- intra-wave lane-crossing gate (b=3..8), tan form ----
template<int D, int B>
__device__ __forceinline__ void gate_lane(float (&st)[NREG], int tid, float t) {
    constexpr unsigned V = axmask(D, B), M = selmask(D, B);
    constexpr int VT = (int)(V >> 3), VR = (int)(V & 7u);
    static_assert(VT > 0 && VT < 64, "intra-wave gate");
    static_assert((M & 7u) == 0, "no reg bits in selector for b>=3");
    const float tp = (__popc((M >> 3) & (unsigned)tid) & 1) ? t : -t;
    if constexpr (VR == 0) {
        sfor<0, NREG>([&](auto RC) {
            constexpr int r = RC.value;
            float p = lxor<VT>(st[r]);      // SIMD-lockstep: reads pre-update
            st[r] = fmaf(tp, p, st[r]);
        });
    } else {
        sfor<0, NREG>([&](auto RC) {
            constexpr int r = RC.value, r2 = r ^ VR;
            if constexpr (r2 > r) {
                float pa = lxor<VT>(st[r2]);
                float pb = lxor<VT>(st[r]);
                st[r]  = fmaf(tp, pa, st[r]);
                st[r2] = fmaf(tp, pb, st[r2]);
            }
        });
    }
}

// ---- fused thread-crossing triple (b=11,10,9): 8 terms, 1 barrier ----
template<int D>
__device__ __forceinline__ void cross3(float (&st)[NREG], int tid,
                                       float t1, float t2, float t9,
                                       float* __restrict__ lds2) {
    constexpr unsigned V1 = axmask(D, 11), V2 = axmask(D, 10), V9 = axmask(D, 9);
    constexpr unsigned M1 = selmask(D, 11), M2 = selmask(D, 10), M9 = selmask(D, 9);
    static_assert(((V1 | V2 | V9) & 7u) == 0, "cross axes reg-free");
    static_assert(((M1 | M2 | M9) & 7u) == 0, "cross masks reg-free");
    constexpr int T1 = (int)(V1 >> 3), T2 = (int)(V2 >> 3), T9 = (int)(V9 >> 3);
    static_assert(T1 > 0 && T2 > 0 && T9 > 0, "thread-crossing");
    // commutation signs: tau_j(i^Vi) = sigma * tau_j(i)
    constexpr int p12 = cpopc(M2 & V1) & 1;
    constexpr int p19 = cpopc(M9 & V1) & 1;
    constexpr int p29 = cpopc(M9 & V2) & 1;
    constexpr int p123 = (p12 + cpopc(M9 & (V1 ^ V2))) & 1;

    const float e1 = (__popc((M1 >> 3) & (unsigned)tid) & 1) ? t1 : -t1;
    const float e2 = (__popc((M2 >> 3) & (unsigned)tid) & 1) ? t2 : -t2;
    const float e9 = (__popc((M9 >> 3) & (unsigned)tid) & 1) ? t9 : -t9;
    const float k12  = (p12  ? -1.f : 1.f) * e1 * e2;
    const float k19  = (p19  ? -1.f : 1.f) * e1 * e9;
    const float k29  = (p29  ? -1.f : 1.f) * e2 * e9;
    const float k123 = (p123 ? -1.f : 1.f) * e1 * e2 * e9;

    float* buf = lds2 + (D & 1) * DIM;
    sfor<0, 2>([&](auto KC) {
        constexpr int k = KC.value;
        *reinterpret_cast<float4*>(&buf[lad(tid, k)]) =
            make_float4(st[4*k], st[4*k+1], st[4*k+2], st[4*k+3]);
    });
    __syncthreads();
    const int q1 = tid ^ T1,        q2 = tid ^ T2,        q9 = tid ^ T9;
    const int q12 = tid ^ (T1^T2),  q19 = tid ^ (T1^T9),  q29 = tid ^ (T2^T9);
    const int q123 = tid ^ (T1^T2^T9);
    sfor<0, 2>([&](auto KC) {
        constexpr int k = KC.value;
        float4 A1 = *reinterpret_cast<const float4*>(&buf[lad(q1,   k)]);
        float4 A2 = *reinterpret_cast<const float4*>(&buf[lad(q2,   k)]);
        float4 A9 = *reinterpret_cast<const float4*>(&buf[lad(q9,   k)]);
        float4 B2 = *reinterpret_cast<const float4*>(&buf[lad(q12,  k)]);
        float4 B9 = *reinterpret_cast<const float4*>(&buf[lad(q19,  k)]);
        float4 C9 = *reinterpret_cast<const float4*>(&buf[lad(q29,  k)]);
        float4 Dv = *reinterpret_cast<const float4*>(&buf[lad(q123, k)]);
        sfor<0, 4>([&](auto EC) {
            constexpr int e = EC.value;
            const float a1 = (e==0)?A1.x:(e==1)?A1.y:(e==2)?A1.z:A1.w;
            const float a2 = (e==0)?A2.x:(e==1)?A2.y:(e==2)?A2.z:A2.w;
            const float a9 = (e==0)?A9.x:(e==1)?A9.y:(e==2)?A9.z:A9.w;
            const float b2 = (e==0)?B2.x:(e==1)?B2.y:(e==2)?B2.z:B2.w;
            const float b9 = (e==0)?B9.x:(e==1)?B9.y:(e==2)?B9.z:B9.w;
            const float c9 = (e==0)?C9.x:(e==1)?C9.y:(e==2)?C9.z:C9.w;
            const float dv = (e==0)?Dv.x:(e==1)?Dv.y:(e==2)?Dv.z:Dv.w;
            float t = st[4*k+e];
            t = fmaf(e1,   a1, t);
            t = fmaf(e2,   a2, t);
            t = fmaf(e9,   a9, t);
            t = fmaf(k12,  b2, t);
            t = fmaf(k19,  b9, t);
            t = fmaf(k29,  c9, t);
            st[4*k+e] = fmaf(k123, dv, t);
        });
    });
}

// ---- one depth: taus from LDS table ----
template<int D>
__device__ __forceinline__ void depth_apply(float (&st)[NREG], int tid,
                                            const float* __restrict__ tsh,
                                            float* __restrict__ lds2) {
    float4 ta = *reinterpret_cast<const float4*>(&tsh[D * 12 + 0]);
    float4 tb = *reinterpret_cast<const float4*>(&tsh[D * 12 + 4]);
    float4 tc = *reinterpret_cast<const float4*>(&tsh[D * 12 + 8]);
    float tq[12] = {ta.x, ta.y, ta.z, ta.w, tb.x, tb.y, tb.z, tb.w,
                    tc.x, tc.y, tc.z, tc.w};
    cross3<D>(st, tid, tq[0], tq[1], tq[2], lds2);   // b = 11, 10, 9
    sfor<3, 12>([&](auto QC) {                       // b = 8..0
        constexpr int Q = QC.value, B = 11 - Q;
        if constexpr (B >= 3) gate_lane<D, B>(st, tid, tq[Q]);
        else                  gate_reg <D, B>(st, tid, tq[Q]);
    });
}

__global__ __launch_bounds__(NT, 2)
void qnet_kernel(const float* __restrict__ x,       // [NBATCH, NQ]
                 const float* __restrict__ thetas,  // [DEPTH, NQ]
                 float* __restrict__ out)           // [NBATCH, 3]
{
    __shared__ __align__(16) float lds2[2 * DIM];   // 32 KB exchange buffers
    __shared__ __align__(16) float tsh[80];         // tan table (72 used)
    __shared__ __align__(16) float csh[80];         // cos table (72 used)
    __shared__ float red[8];                        // per-wave sums

    const int b   = blockIdx.x;
    const int tid = threadIdx.x;

    // ---- gate trig tables, once per block ----
    if (tid < 72) {
        float rev = thetas[tid] * 0.07957747154594767f;  // (th/2)/(2pi)
        float cc  = __builtin_amdgcn_cosf(rev);
        float ss  = __builtin_amdgcn_sinf(rev);
        csh[tid] = cc;
        tsh[tid] = ss * __builtin_amdgcn_rcpf(cc);
    }

    // ---- encoder: x*pi/2 rad = x/4 rev ----
    const float4* xv = reinterpret_cast<const float4*>(x + b * 12);
    float4 xa = xv[0], xb = xv[1], xc = xv[2];
    float xs[12] = {xa.x, xa.y, xa.z, xa.w, xb.x, xb.y, xb.z, xb.w,
                    xc.x, xc.y, xc.z, xc.w};
    float cq[12], sq[12];
    sfor<0, 12>([&](auto QC) {
        constexpr int q = QC.value;
        float rev = xs[q] * 0.25f;
        sq[q] = __builtin_amdgcn_sinf(rev);
        cq[q] = __builtin_amdgcn_cosf(rev);
    });

    // product state: j = (tid<<3)|r; j bit (3+i) = tid bit i <-> qubit 8-i;
    // j bit i (i<3) = reg bit i <-> qubit 11-i
    float la = 1.0f;
    sfor<0, 9>([&](auto IC) {
        constexpr int i = IC.value;
        la *= ((tid >> i) & 1) ? sq[8 - i] : cq[8 - i];
    });
    float st[NREG];
    st[0] = la;
    sfor<0, 3>([&](auto IC) {
        constexpr int i = IC.value;
        sfor<0, (1 << i)>([&](auto KC) {
            constexpr int k = KC.value;
            float base = st[k];
            st[k + (1 << i)] = base * sq[11 - i];
            st[k]            = base * cq[11 - i];
        });
    });

    __syncthreads();   // trig tables ready

    // ---- 6 depths, one barrier each (inside cross3) ----
    sfor<0, 6>([&](auto DC) {
        depth_apply<DC.value>(st, tid, tsh, lds2);
    });

    // ---- global scale: sc = prod of all 72 cos ----
    float sc = 1.0f;
    sfor<0, 18>([&](auto IC) {
        constexpr int i = IC.value;
        float4 c4 = *reinterpret_cast<const float4*>(&csh[4 * i]);
        sc *= (c4.x * c4.y) * (c4.z * c4.w);
    });

    // ---- observer ----
    float tot = 0.0f;
    sfor<0, NREG>([&](auto RC) {
        constexpr int r = RC.value;
        tot = fmaf(st[r], st[r], tot);
    });
    tot *= sc * sc;   // undo tan normalization once

    // full 64-lane butterfly sum
    float v = tot;
    v += lxor<1>(v);
    v += lxor<2>(v);
    v += lxor<4>(v);
    v += lxor<8>(v);
    v += lxor<16>(v);
    v += lxor<32>(v);
    const int w = tid >> 6;
    if ((tid & 63) == 0) red[w] = v;
    __syncthreads();
    // signs on stored index: q0 -> j bit 11 = w bit 2; q1 -> j bit 10 = w bit 1;
    // q2 -> j bits 11^9 = w bits 2^0
    if (tid < 3) {
        float acc = 0.0f;
        #pragma unroll
        for (int ww = 0; ww < 8; ++ww) {
            int par = (tid == 0) ? ((ww >> 2) & 1)
                    : (tid == 1) ? ((ww >> 1) & 1)
                    :              (((ww >> 2) ^ ww) & 1);
            acc += par ? -red[ww] : red[ww];
        }
        out[b * 3 + tid] = acc;
    }
}

extern "C" void kernel_launch(void* const* d_in, const int* in_sizes, int n_in,
                              void* d_out, int out_size, void* d_ws, size_t ws_size,
                              hipStream_t stream) {
    (void)in_sizes; (void)n_in; (void)out_size; (void)d_ws; (void)ws_size;
    const float* x      = (const float*)d_in[0];   // [256,12] f32
    const float* thetas = (const float*)d_in[1];   // [6,12]   f32
    float* out          = (float*)d_out;           // [256,3]  f32

    qnet_kernel<<<dim3(NBATCH), dim3(NT), 0, stream>>>(x, thetas, out);
}

// Round 11
// 16.062 us; speedup vs baseline: 1.0226x; 1.0226x over previous
//
#include <hip/hip_runtime.h>
#include <math.h>
#include <type_traits>

#define NQ     12
#define DIM    4096
#define DEPTH  6
#define NBATCH 256
#define NT     512     // 8 waves per block -> 2 waves per SIMD
#define NREG   8       // state elements per thread

#if defined(__has_builtin)
#  if __has_builtin(__builtin_amdgcn_permlane16_swap) && __has_builtin(__builtin_amdgcn_permlane32_swap)
#    define USE_PERMLANE 1
#  else
#    define USE_PERMLANE 0
#  endif
#else
#  define USE_PERMLANE 0
#endif

// ---------------------------------------------------------------------------
// CNOT-ladder perm = Gray map g(j)=j^(j>>1), linear over GF(2)^12; all perms
// folded into gates: depth-d gate on logical bit b = butterfly on XOR-axis
// V = A^d e_b, sign selector M = row b of A^{-d} (A^16=I):
//   new[j] = x[j] + tau(j)*x[j^V],  tau(j) = parity(M&j) ? +t : -t, t=tan(th/2)
// (tan-normalized; global scale prod(cos) applied once in the observer).
// Storage j = (tid<<3)|r, tid 0..511, r 0..7.
//
// ROUND 11 = best-of-R9/R10:
//  - R9 exchange structure (cross2 fused pair b=11,10 + separate gate9x;
//    12 float4 DS ops + 2 barriers per depth). R10's cross3 regression showed
//    LDS op count dominates barrier count on this kernel.
//  - R10's PROVEN permlane16/32_swap builtins for all intra-wave lane xors
//    (xor-combine r[0]^r[1]^u is operand-convention-independent. R6/R8
//    failures were inline-asm "+v"(a),"+v"(b) register aliasing -> self-swap;
//    asm form stays banned). DS pipe now carries only the cross exchanges.
//  - Depth order: cross2 -> lane/reg gates (VALU) -> gate9x, so the VALU gate
//    block sits between the two LDS round trips (gates of a depth commute).
// ---------------------------------------------------------------------------

__host__ __device__ constexpr unsigned axmask(int d, int b) {
    unsigned m = 1u << b;
    for (int i = 0; i < d; ++i) m = (m ^ (m >> 1)) & 0xFFFu;
    return m;
}
__host__ __device__ constexpr unsigned selmask(int d, int b) {
    unsigned m = 1u << b;
    for (int i = 0; i < 16 - d; ++i) m = (m ^ ((m << 1) & 0xFFFu)) & 0xFFFu;
    return m;
}
__host__ __device__ constexpr int cpopc(unsigned v) {
    int c = 0; while (v) { c += (int)(v & 1u); v >>= 1; } return c;
}

template<int I, int N, class F>
__device__ __forceinline__ void sfor(F&& f) {
    if constexpr (I < N) {
        f(std::integral_constant<int, I>{});
        sfor<I + 1, N>(static_cast<F&&>(f));
    }
}

// ---- cross-lane primitives ----
template<int CTRL>
__device__ __forceinline__ float dppx(float v) {
    int iv = __float_as_int(v);
    return __int_as_float(__builtin_amdgcn_update_dpp(iv, iv, CTRL, 0xF, 0xF, false));
}
template<int M4>
__device__ __forceinline__ float lxor_low(float v) {
    static_assert(M4 >= 1 && M4 <= 15, "low mask");
    if constexpr      (M4 == 1)  return dppx<0xB1>(v);    // quad_perm xor1
    else if constexpr (M4 == 2)  return dppx<0x4E>(v);    // quad_perm xor2
    else if constexpr (M4 == 3)  return dppx<0x1B>(v);    // quad_perm xor3
    else if constexpr (M4 == 7)  return dppx<0x141>(v);   // row_half_mirror
    else if constexpr (M4 == 15) return dppx<0x140>(v);   // row_mirror
    else if constexpr ((M4 & 8) == 0)   // 4,5,6 = 7 ^ {3,2,1}
        return lxor_low<M4 ^ 7>(dppx<0x141>(v));
    else                                // 8..14 = 15 ^ {7..1}
        return lxor_low<M4 ^ 15>(dppx<0x140>(v));
}

#if USE_PERMLANE
typedef unsigned u32x2 __attribute__((ext_vector_type(2)));
__device__ __forceinline__ float plx16(float v) {
    unsigned u = __float_as_uint(v);
    u32x2 r = __builtin_amdgcn_permlane16_swap(u, u, false, false);
    return __uint_as_float(r[0] ^ r[1] ^ u);   // own-term cancels -> partner
}
__device__ __forceinline__ float plx32(float v) {
    unsigned u = __float_as_uint(v);
    u32x2 r = __builtin_amdgcn_permlane32_swap(u, u, false, false);
    return __uint_as_float(r[0] ^ r[1] ^ u);
}
template<int MASK>
__device__ __forceinline__ float lxor(float v) {
    static_assert(MASK > 0 && MASK < 64, "lane mask");
    float r = v;
    if constexpr (MASK & 32) r = plx32(r);
    if constexpr (MASK & 16) r = plx16(r);
    if constexpr (MASK & 15) r = lxor_low<MASK & 15>(r);
    return r;
}
#else
template<int MASK>
__device__ __forceinline__ float lxor(float v) {
    static_assert(MASK > 0 && MASK < 64, "lane mask");
    if constexpr (MASK >= 32) {
        return __shfl_xor(v, MASK, 64);
    } else if constexpr (MASK >= 16) {
        return __int_as_float(__builtin_amdgcn_ds_swizzle(__float_as_int(v),
                                                          (MASK << 10) | 0x1F));
    } else {
        return lxor_low<MASK>(v);
    }
}
#endif

// swizzled LDS word address: thread t, chunk k in 0..1, 8 floats/thread
__device__ __forceinline__ int lad(int t, int k) {
    return t * 8 + 4 * (k ^ ((t >> 2) & 1));
}

// ---- pure-register gate (b<=2), tan form: 1 fma/elem ----
template<int D, int B>
__device__ __forceinline__ void gate_reg(float (&st)[NREG], int tid, float t) {
    constexpr unsigned V = axmask(D, B), M = selmask(D, B);
    static_assert((V >> 3) == 0 && V != 0, "reg gate");
    constexpr int VR = (int)V;
    constexpr unsigned MR = M & 7u, MT = M >> 3;
    const float tp = (__popc(MT & (unsigned)tid) & 1) ? t : -t;
    const float tn = -tp;
    sfor<0, NREG>([&](auto RC) {
        constexpr int r = RC.value, r2 = r ^ VR;
        if constexpr (r2 > r) {
            constexpr bool p0 = (cpopc(MR & (unsigned)r)  & 1) != 0;
            constexpr bool p1 = (cpopc(MR & (unsigned)r2) & 1) != 0;
            float a0 = st[r];
            st[r]  = fmaf(p0 ? tn : tp, st[r2], st[r]);
            st[r2] = fmaf(p1 ? tn : tp, a0,     st[r2]);
        }
    });
}

// ---- intra-wave lane-crossing gate (b=3..8), tan form, all-VALU ----
template<int D, int B>
__device__ __forceinline__ void gate_lane(float (&st)[NREG], int tid, float t) {
    constexpr unsigned V = axmask(D, B), M = selmask(D, B);
    constexpr int VT = (int)(V >> 3), VR = (int)(V & 7u);
    static_assert(VT > 0 && VT < 64, "intra-wave gate");
    static_assert((M & 7u) == 0, "no reg bits in selector for b>=3");
    const float tp = (__popc((M >> 3) & (unsigned)tid) & 1) ? t : -t;
    if constexpr (VR == 0) {
        sfor<0, NREG>([&](auto RC) {
            constexpr int r = RC.value;
            float p = lxor<VT>(st[r]);      // SIMD-lockstep: reads pre-update
            st[r] = fmaf(tp, p, st[r]);
        });
    } else {
        sfor<0, NREG>([&](auto RC) {
            constexpr int r = RC.value, r2 = r ^ VR;
            if constexpr (r2 > r) {
                float pa = lxor<VT>(st[r2]);
                float pb = lxor<VT>(st[r]);
                st[r]  = fmaf(tp, pa, st[r]);
                st[r2] = fmaf(tp, pb, st[r2]);
            }
        });
    }
}

// ---- b=9 gate: LDS pair exchange (crosses wave bits) ----
template<int D>
__device__ __forceinline__ void gate9x(float (&st)[NREG], int tid, float t,
                                       float* __restrict__ lds9) {
    constexpr unsigned V = axmask(D, 9), M = selmask(D, 9);
    static_assert((V & 7u) == 0 && (M & 7u) == 0, "b9 reg-pure-free");
    constexpr int T = (int)(V >> 3);
    static_assert(T >= 64 && T < 512, "b9 crosses waves");
    const float tp = (__popc((M >> 3) & (unsigned)tid) & 1) ? t : -t;
    float* buf = lds9 + (D & 1) * DIM;
    sfor<0, 2>([&](auto KC) {
        constexpr int k = KC.value;
        *reinterpret_cast<float4*>(&buf[lad(tid, k)]) =
            make_float4(st[4*k], st[4*k+1], st[4*k+2], st[4*k+3]);
    });
    __syncthreads();
    const int p = tid ^ T;
    sfor<0, 2>([&](auto KC) {
        constexpr int k = KC.value;
        float4 pv = *reinterpret_cast<const float4*>(&buf[lad(p, k)]);
        st[4*k+0] = fmaf(tp, pv.x, st[4*k+0]);
        st[4*k+1] = fmaf(tp, pv.y, st[4*k+1]);
        st[4*k+2] = fmaf(tp, pv.z, st[4*k+2]);
        st[4*k+3] = fmaf(tp, pv.w, st[4*k+3]);
    });
}

// ---- fused cross pair (b=11,10), tan form: 3 fma/elem ----
template<int D>
__device__ __forceinline__ void cross2(float (&st)[NREG], int tid,
                                       float t1, float t2,
                                       float* __restrict__ lds2) {
    constexpr unsigned V1 = axmask(D, 11), V2 = axmask(D, 10);
    constexpr unsigned M1 = selmask(D, 11), M2 = selmask(D, 10);
    static_assert((V1 & 7u) == 0 && (V2 & 7u) == 0, "cross axes reg-free");
    static_assert((M1 & 7u) == 0 && (M2 & 7u) == 0, "cross masks reg-free");
    constexpr int T1 = (int)(V1 >> 3), T2 = (int)(V2 >> 3);
    static_assert((cpopc(M1 & V2) & 1) == 0, "kC sign identity");

    const float t1p = (__popc((M1 >> 3) & (unsigned)tid) & 1) ? t1 : -t1;
    const float t2p = (__popc((M2 >> 3) & (unsigned)tid) & 1) ? t2 : -t2;
    const float t12 = t1p * t2p;

    float* buf = lds2 + (D & 1) * DIM;
    sfor<0, 2>([&](auto KC) {
        constexpr int k = KC.value;
        *reinterpret_cast<float4*>(&buf[lad(tid, k)]) =
            make_float4(st[4*k], st[4*k+1], st[4*k+2], st[4*k+3]);
    });
    __syncthreads();
    const int p1 = tid ^ T1, p2 = tid ^ T2, p3 = tid ^ (T1 ^ T2);
    sfor<0, 2>([&](auto KC) {
        constexpr int k = KC.value;
        float4 A  = *reinterpret_cast<const float4*>(&buf[lad(p1, k)]);
        float4 Bv = *reinterpret_cast<const float4*>(&buf[lad(p2, k)]);
        float4 Cv = *reinterpret_cast<const float4*>(&buf[lad(p3, k)]);
        float t;
        t = fmaf(t1p, A.x, st[4*k+0]); t = fmaf(t2p, Bv.x, t); st[4*k+0] = fmaf(t12, Cv.x, t);
        t = fmaf(t1p, A.y, st[4*k+1]); t = fmaf(t2p, Bv.y, t); st[4*k+1] = fmaf(t12, Cv.y, t);
        t = fmaf(t1p, A.z, st[4*k+2]); t = fmaf(t2p, Bv.z, t); st[4*k+2] = fmaf(t12, Cv.z, t);
        t = fmaf(t1p, A.w, st[4*k+3]); t = fmaf(t2p, Bv.w, t); st[4*k+3] = fmaf(t12, Cv.w, t);
    });
}

// ---- one depth: cross2 -> VALU gates -> gate9x (all gates commute) ----
template<int D>
__device__ __forceinline__ void depth_apply(float (&st)[NREG], int tid,
                                            const float* __restrict__ tsh,
                                            float* __restrict__ lds2,
                                            float* __restrict__ lds9) {
    float4 ta = *reinterpret_cast<const float4*>(&tsh[D * 12 + 0]);
    float4 tb = *reinterpret_cast<const float4*>(&tsh[D * 12 + 4]);
    float4 tc = *reinterpret_cast<const float4*>(&tsh[D * 12 + 8]);
    float tq[12] = {ta.x, ta.y, ta.z, ta.w, tb.x, tb.y, tb.z, tb.w,
                    tc.x, tc.y, tc.z, tc.w};
    cross2<D>(st, tid, tq[0], tq[1], lds2);    // b = 11, 10 (LDS)
    sfor<3, 12>([&](auto QC) {                 // b = 8..0 (pure VALU)
        constexpr int Q = QC.value, B = 11 - Q;
        if constexpr (B >= 3) gate_lane<D, B>(st, tid, tq[Q]);
        else                  gate_reg <D, B>(st, tid, tq[Q]);
    });
    gate9x<D>(st, tid, tq[2], lds9);           // b = 9 (LDS)
}

__global__ __launch_bounds__(NT, 2)
void qnet_kernel(const float* __restrict__ x,       // [NBATCH, NQ]
                 const float* __restrict__ thetas,  // [DEPTH, NQ]
                 float* __restrict__ out)           // [NBATCH, 3]
{
    __shared__ __align__(16) float lds2[2 * DIM];   // 32 KB cross2 buffers
    __shared__ __align__(16) float lds9[2 * DIM];   // 32 KB gate9 buffers
    __shared__ __align__(16) float tsh[80];         // tan table (72 used)
    __shared__ __align__(16) float csh[80];         // cos table (72 used)
    __shared__ float red[8];                        // per-wave sums

    const int b   = blockIdx.x;
    const int tid = threadIdx.x;

    // ---- gate trig tables, once per block ----
    if (tid < 72) {
        float rev = thetas[tid] * 0.07957747154594767f;  // (th/2)/(2pi)
        float cc  = __builtin_amdgcn_cosf(rev);
        float ss  = __builtin_amdgcn_sinf(rev);
        csh[tid] = cc;
        tsh[tid] = ss * __builtin_amdgcn_rcpf(cc);
    }

    // ---- encoder: x*pi/2 rad = x/4 rev ----
    const float4* xv = reinterpret_cast<const float4*>(x + b * 12);
    float4 xa = xv[0], xb = xv[1], xc = xv[2];
    float xs[12] = {xa.x, xa.y, xa.z, xa.w, xb.x, xb.y, xb.z, xb.w,
                    xc.x, xc.y, xc.z, xc.w};
    float cq[12], sq[12];
    sfor<0, 12>([&](auto QC) {
        constexpr int q = QC.value;
        float rev = xs[q] * 0.25f;
        sq[q] = __builtin_amdgcn_sinf(rev);
        cq[q] = __builtin_amdgcn_cosf(rev);
    });

    // product state: j = (tid<<3)|r; j bit (3+i) = tid bit i <-> qubit 8-i;
    // j bit i (i<3) = reg bit i <-> qubit 11-i
    float la = 1.0f;
    sfor<0, 9>([&](auto IC) {
        constexpr int i = IC.value;
        la *= ((tid >> i) & 1) ? sq[8 - i] : cq[8 - i];
    });
    float st[NREG];
    st[0] = la;
    sfor<0, 3>([&](auto IC) {
        constexpr int i = IC.value;
        sfor<0, (1 << i)>([&](auto KC) {
            constexpr int k = KC.value;
            float base = st[k];
            st[k + (1 << i)] = base * sq[11 - i];
            st[k]            = base * cq[11 - i];
        });
    });

    __syncthreads();   // trig tables ready

    // ---- 6 depths ----
    sfor<0, 6>([&](auto DC) {
        depth_apply<DC.value>(st, tid, tsh, lds2, lds9);
    });

    // ---- global scale: sc = prod of all 72 cos ----
    float sc = 1.0f;
    sfor<0, 18>([&](auto IC) {
        constexpr int i = IC.value;
        float4 c4 = *reinterpret_cast<const float4*>(&csh[4 * i]);
        sc *= (c4.x * c4.y) * (c4.z * c4.w);
    });

    // ---- observer ----
    float tot = 0.0f;
    sfor<0, NREG>([&](auto RC) {
        constexpr int r = RC.value;
        tot = fmaf(st[r], st[r], tot);
    });
    tot *= sc * sc;   // undo tan normalization once

    // full 64-lane butterfly sum
    float v = tot;
    v += lxor<1>(v);
    v += lxor<2>(v);
    v += lxor<4>(v);
    v += lxor<8>(v);
    v += lxor<16>(v);
    v += lxor<32>(v);
    const int w = tid >> 6;
    if ((tid & 63) == 0) red[w] = v;
    __syncthreads();
    // signs on stored index: q0 -> j bit 11 = w bit 2; q1 -> j bit 10 = w bit 1;
    // q2 -> j bits 11^9 = w bits 2^0
    if (tid < 3) {
        float acc = 0.0f;
        #pragma unroll
        for (int ww = 0; ww < 8; ++ww) {
            int par = (tid == 0) ? ((ww >> 2) & 1)
                    : (tid == 1) ? ((ww >> 1) & 1)
                    :              (((ww >> 2) ^ ww) & 1);
            acc += par ? -red[ww] : red[ww];
        }
        out[b * 3 + tid] = acc;
    }
}

extern "C" void kernel_launch(void* const* d_in, const int* in_sizes, int n_in,
                              void* d_out, int out_size, void* d_ws, size_t ws_size,
                              hipStream_t stream) {
    (void)in_sizes; (void)n_in; (void)out_size; (void)d_ws; (void)ws_size;
    const float* x      = (const float*)d_in[0];   // [256,12] f32
    const float* thetas = (const float*)d_in[1];   // [6,12]   f32
    float* out          = (float*)d_out;           // [256,3]  f32

    qnet_kernel<<<dim3(NBATCH), dim3(NT), 0, stream>>>(x, thetas, out);
}

// Round 12
// 14.606 us; speedup vs baseline: 1.1245x; 1.0997x over previous
//
#include <hip/hip_runtime.h>
#include <math.h>
#include <type_traits>

#define NQ     12
#define DIM    4096
#define DEPTH  6
#define NBATCH 256
#define NT     512     // 8 waves per block -> 2 waves per SIMD
#define NREG   8       // state elements per thread

// ---------------------------------------------------------------------------
// CNOT-ladder perm = Gray map g(j)=j^(j>>1), linear over GF(2)^12; all perms
// folded into gates: depth-d gate on logical bit b = butterfly on XOR-axis
// V = A^d e_b, sign selector M = row b of A^{-d} (A^16=I):
//   new[j] = x[j] + tau(j)*x[j^V],  tau(j) = parity(M&j) ? +t : -t, t=tan(th/2)
// (tan-normalized; global scale prod(cos) applied once in the observer).
// Storage j = (tid<<3)|r, tid 0..511, r 0..7.
//   b<=2   -> register butterfly
//   b=3..8 -> intra-wave lane-xor: DPP(<16) / ds_swizzle(16..31) / shfl(>=32)
//             (permlane16/32_swap retired: R10/R11 measured net-negative)
//   b=9    -> LDS pair exchange; b=10,11 -> fused cross2. 2 barriers/depth.
//
// ROUND 12 = R9 (best, 14.38us) + ONE change: lds2 padded so static LDS
// (~88 KB) exceeds 160/2 KB -> the dispatcher CANNOT co-schedule 2 blocks
// on one CU. Hypothesis: with ~64.7 KB, some CUs packed 2 of the 256 blocks
// (grid == CU count; placement undefined) -> 2x tail = the unexplained gap
// between ~6-7us issued-work estimate and 14.4us measured. If packing was
// real: expect ~8-9.5us. If neutral: gap is replay overhead / barrier
// convergence and we are near the structural floor.
// ---------------------------------------------------------------------------

#define LDS2PAD 5440   // pad floats: total static LDS ~88 KB > 81920 B

__host__ __device__ constexpr unsigned axmask(int d, int b) {
    unsigned m = 1u << b;
    for (int i = 0; i < d; ++i) m = (m ^ (m >> 1)) & 0xFFFu;
    return m;
}
__host__ __device__ constexpr unsigned selmask(int d, int b) {
    unsigned m = 1u << b;
    for (int i = 0; i < 16 - d; ++i) m = (m ^ ((m << 1) & 0xFFFu)) & 0xFFFu;
    return m;
}
__host__ __device__ constexpr int cpopc(unsigned v) {
    int c = 0; while (v) { c += (int)(v & 1u); v >>= 1; } return c;
}

template<int I, int N, class F>
__device__ __forceinline__ void sfor(F&& f) {
    if constexpr (I < N) {
        f(std::integral_constant<int, I>{});
        sfor<I + 1, N>(static_cast<F&&>(f));
    }
}

// ---- cross-lane primitives (R5/R7/R9-proven set ONLY) ----
template<int CTRL>
__device__ __forceinline__ float dppx(float v) {
    int iv = __float_as_int(v);
    return __int_as_float(__builtin_amdgcn_update_dpp(iv, iv, CTRL, 0xF, 0xF, false));
}
template<int M4>
__device__ __forceinline__ float lxor_low(float v) {
    static_assert(M4 >= 1 && M4 <= 15, "low mask");
    if constexpr      (M4 == 1)  return dppx<0xB1>(v);    // quad_perm xor1
    else if constexpr (M4 == 2)  return dppx<0x4E>(v);    // quad_perm xor2
    else if constexpr (M4 == 3)  return dppx<0x1B>(v);    // quad_perm xor3
    else if constexpr (M4 == 7)  return dppx<0x141>(v);   // row_half_mirror
    else if constexpr (M4 == 15) return dppx<0x140>(v);   // row_mirror
    else if constexpr ((M4 & 8) == 0)   // 4,5,6 = 7 ^ {3,2,1}
        return lxor_low<M4 ^ 7>(dppx<0x141>(v));
    else                                // 8..14 = 15 ^ {7..1}
        return lxor_low<M4 ^ 15>(dppx<0x140>(v));
}
template<int MASK>
__device__ __forceinline__ float lxor(float v) {
    static_assert(MASK > 0 && MASK < 64, "lane mask");
    if constexpr (MASK >= 32) {
        return __shfl_xor(v, MASK, 64);
    } else if constexpr (MASK >= 16) {
        // ds_swizzle BitMode: (xor<<10) | (or<<5) | and(0x1F)
        return __int_as_float(__builtin_amdgcn_ds_swizzle(__float_as_int(v),
                                                          (MASK << 10) | 0x1F));
    } else {
        return lxor_low<MASK>(v);
    }
}

// swizzled LDS word address: thread t, chunk k in 0..1, 8 floats/thread
__device__ __forceinline__ int lad(int t, int k) {
    return t * 8 + 4 * (k ^ ((t >> 2) & 1));
}

// ---- pure-register gate (b<=2), tan form: 1 fma/elem ----
template<int D, int B>
__device__ __forceinline__ void gate_reg(float (&st)[NREG], int tid, float t) {
    constexpr unsigned V = axmask(D, B), M = selmask(D, B);
    static_assert((V >> 3) == 0 && V != 0, "reg gate");
    constexpr int VR = (int)V;
    constexpr unsigned MR = M & 7u, MT = M >> 3;
    const float tp = (__popc(MT & (unsigned)tid) & 1) ? t : -t;
    const float tn = -tp;
    sfor<0, NREG>([&](auto RC) {
        constexpr int r = RC.value, r2 = r ^ VR;
        if constexpr (r2 > r) {
            constexpr bool p0 = (cpopc(MR & (unsigned)r)  & 1) != 0;
            constexpr bool p1 = (cpopc(MR & (unsigned)r2) & 1) != 0;
            float a0 = st[r];
            st[r]  = fmaf(p0 ? tn : tp, st[r2], st[r]);
            st[r2] = fmaf(p1 ? tn : tp, a0,     st[r2]);
        }
    });
}

// ---- intra-wave lane-crossing gate (b=3..8), tan form ----
template<int D, int B>
__device__ __forceinline__ void gate_lane(float (&st)[NREG], int tid, float t) {
    constexpr unsigned V = axmask(D, B), M = selmask(D, B);
    constexpr int VT = (int)(V >> 3), VR = (int)(V & 7u);
    static_assert(VT > 0 && VT < 64, "intra-wave gate");
    static_assert((M & 7u) == 0, "no reg bits in selector for b>=3");
    const float tp = (__popc((M >> 3) & (unsigned)tid) & 1) ? t : -t;
    if constexpr (VR == 0) {
        sfor<0, NREG>([&](auto RC) {
            constexpr int r = RC.value;
            float p = lxor<VT>(st[r]);      // SIMD-lockstep: reads pre-update
            st[r] = fmaf(tp, p, st[r]);
        });
    } else {
        sfor<0, NREG>([&](auto RC) {
            constexpr int r = RC.value, r2 = r ^ VR;
            if constexpr (r2 > r) {
                float pa = lxor<VT>(st[r2]);
                float pb = lxor<VT>(st[r]);
                st[r]  = fmaf(tp, pa, st[r]);
                st[r2] = fmaf(tp, pb, st[r2]);
            }
        });
    }
}

// ---- b=9 gate: LDS pair exchange (crosses wave bits) ----
template<int D>
__device__ __forceinline__ void gate9x(float (&st)[NREG], int tid, float t,
                                       float* __restrict__ lds9) {
    constexpr unsigned V = axmask(D, 9), M = selmask(D, 9);
    static_assert((V & 7u) == 0 && (M & 7u) == 0, "b9 reg-pure-free");
    constexpr int T = (int)(V >> 3);
    static_assert(T >= 64 && T < 512, "b9 crosses waves");
    const float tp = (__popc((M >> 3) & (unsigned)tid) & 1) ? t : -t;
    float* buf = lds9 + (D & 1) * DIM;
    sfor<0, 2>([&](auto KC) {
        constexpr int k = KC.value;
        *reinterpret_cast<float4*>(&buf[lad(tid, k)]) =
            make_float4(st[4*k], st[4*k+1], st[4*k+2], st[4*k+3]);
    });
    __syncthreads();
    const int p = tid ^ T;
    sfor<0, 2>([&](auto KC) {
        constexpr int k = KC.value;
        float4 pv = *reinterpret_cast<const float4*>(&buf[lad(p, k)]);
        st[4*k+0] = fmaf(tp, pv.x, st[4*k+0]);
        st[4*k+1] = fmaf(tp, pv.y, st[4*k+1]);
        st[4*k+2] = fmaf(tp, pv.z, st[4*k+2]);
        st[4*k+3] = fmaf(tp, pv.w, st[4*k+3]);
    });
}

// ---- fused cross pair (b=11,10), tan form: 3 fma/elem ----
template<int D>
__device__ __forceinline__ void cross2(float (&st)[NREG], int tid,
                                       float t1, float t2,
                                       float* __restrict__ lds2) {
    constexpr unsigned V1 = axmask(D, 11), V2 = axmask(D, 10);
    constexpr unsigned M1 = selmask(D, 11), M2 = selmask(D, 10);
    static_assert((V1 & 7u) == 0 && (V2 & 7u) == 0, "cross axes reg-free");
    static_assert((M1 & 7u) == 0 && (M2 & 7u) == 0, "cross masks reg-free");
    constexpr int T1 = (int)(V1 >> 3), T2 = (int)(V2 >> 3);
    static_assert((cpopc(M1 & V2) & 1) == 0, "kC sign identity");

    const float t1p = (__popc((M1 >> 3) & (unsigned)tid) & 1) ? t1 : -t1;
    const float t2p = (__popc((M2 >> 3) & (unsigned)tid) & 1) ? t2 : -t2;
    const float t12 = t1p * t2p;

    float* buf = lds2 + (D & 1) * DIM;
    sfor<0, 2>([&](auto KC) {
        constexpr int k = KC.value;
        *reinterpret_cast<float4*>(&buf[lad(tid, k)]) =
            make_float4(st[4*k], st[4*k+1], st[4*k+2], st[4*k+3]);
    });
    __syncthreads();
    const int p1 = tid ^ T1, p2 = tid ^ T2, p3 = tid ^ (T1 ^ T2);
    sfor<0, 2>([&](auto KC) {
        constexpr int k = KC.value;
        float4 A  = *reinterpret_cast<const float4*>(&buf[lad(p1, k)]);
        float4 Bv = *reinterpret_cast<const float4*>(&buf[lad(p2, k)]);
        float4 Cv = *reinterpret_cast<const float4*>(&buf[lad(p3, k)]);
        float t;
        t = fmaf(t1p, A.x, st[4*k+0]); t = fmaf(t2p, Bv.x, t); st[4*k+0] = fmaf(t12, Cv.x, t);
        t = fmaf(t1p, A.y, st[4*k+1]); t = fmaf(t2p, Bv.y, t); st[4*k+1] = fmaf(t12, Cv.y, t);
        t = fmaf(t1p, A.z, st[4*k+2]); t = fmaf(t2p, Bv.z, t); st[4*k+2] = fmaf(t12, Cv.z, t);
        t = fmaf(t1p, A.w, st[4*k+3]); t = fmaf(t2p, Bv.w, t); st[4*k+3] = fmaf(t12, Cv.w, t);
    });
}

// ---- one depth: taus from LDS table (R9 order: cross2 -> gate9x -> VALU) ----
template<int D>
__device__ __forceinline__ void depth_apply(float (&st)[NREG], int tid,
                                            const float* __restrict__ tsh,
                                            float* __restrict__ lds2,
                                            float* __restrict__ lds9) {
    float4 ta = *reinterpret_cast<const float4*>(&tsh[D * 12 + 0]);
    float4 tb = *reinterpret_cast<const float4*>(&tsh[D * 12 + 4]);
    float4 tc = *reinterpret_cast<const float4*>(&tsh[D * 12 + 8]);
    float tq[12] = {ta.x, ta.y, ta.z, ta.w, tb.x, tb.y, tb.z, tb.w,
                    tc.x, tc.y, tc.z, tc.w};
    cross2<D>(st, tid, tq[0], tq[1], lds2);    // b = 11, 10
    gate9x<D>(st, tid, tq[2], lds9);           // b = 9
    sfor<3, 12>([&](auto QC) {                 // b = 8..0
        constexpr int Q = QC.value, B = 11 - Q;
        if constexpr (B >= 3) gate_lane<D, B>(st, tid, tq[Q]);
        else                  gate_reg <D, B>(st, tid, tq[Q]);
    });
}

__global__ __launch_bounds__(NT, 2)
void qnet_kernel(const float* __restrict__ x,       // [NBATCH, NQ]
                 const float* __restrict__ thetas,  // [DEPTH, NQ]
                 float* __restrict__ out)           // [NBATCH, 3]
{
    // lds2 padded: total static LDS ~88 KB -> at most ONE block per CU.
    __shared__ __align__(16) float lds2[2 * DIM + LDS2PAD];
    __shared__ __align__(16) float lds9[2 * DIM];   // 32 KB gate9 buffers
    __shared__ __align__(16) float tsh[80];         // tan table (72 used)
    __shared__ __align__(16) float csh[80];         // cos table (72 used)
    __shared__ float red[8];                        // per-wave sums

    const int b   = blockIdx.x;
    const int tid = threadIdx.x;

    // ---- gate trig tables, once per block ----
    if (tid < 72) {
        float rev = thetas[tid] * 0.07957747154594767f;  // (th/2)/(2pi)
        float cc  = __builtin_amdgcn_cosf(rev);
        float ss  = __builtin_amdgcn_sinf(rev);
        csh[tid] = cc;
        tsh[tid] = ss * __builtin_amdgcn_rcpf(cc);
    }

    // ---- encoder: x*pi/2 rad = x/4 rev ----
    const float4* xv = reinterpret_cast<const float4*>(x + b * 12);
    float4 xa = xv[0], xb = xv[1], xc = xv[2];
    float xs[12] = {xa.x, xa.y, xa.z, xa.w, xb.x, xb.y, xb.z, xb.w,
                    xc.x, xc.y, xc.z, xc.w};
    float cq[12], sq[12];
    sfor<0, 12>([&](auto QC) {
        constexpr int q = QC.value;
        float rev = xs[q] * 0.25f;
        sq[q] = __builtin_amdgcn_sinf(rev);
        cq[q] = __builtin_amdgcn_cosf(rev);
    });

    // product state: j = (tid<<3)|r; j bit (3+i) = tid bit i <-> qubit 8-i;
    // j bit i (i<3) = reg bit i <-> qubit 11-i
    float la = 1.0f;
    sfor<0, 9>([&](auto IC) {
        constexpr int i = IC.value;
        la *= ((tid >> i) & 1) ? sq[8 - i] : cq[8 - i];
    });
    float st[NREG];
    st[0] = la;
    sfor<0, 3>([&](auto IC) {
        constexpr int i = IC.value;
        sfor<0, (1 << i)>([&](auto KC) {
            constexpr int k = KC.value;
            float base = st[k];
            st[k + (1 << i)] = base * sq[11 - i];
            st[k]            = base * cq[11 - i];
        });
    });

    __syncthreads();   // trig tables ready

    // ---- 6 depths ----
    sfor<0, 6>([&](auto DC) {
        depth_apply<DC.value>(st, tid, tsh, lds2, lds9);
    });

    // ---- global scale: sc = prod of all 72 cos ----
    float sc = 1.0f;
    sfor<0, 18>([&](auto IC) {
        constexpr int i = IC.value;
        float4 c4 = *reinterpret_cast<const float4*>(&csh[4 * i]);
        sc *= (c4.x * c4.y) * (c4.z * c4.w);
    });

    // ---- observer ----
    float tot = 0.0f;
    sfor<0, NREG>([&](auto RC) {
        constexpr int r = RC.value;
        tot = fmaf(st[r], st[r], tot);
    });
    tot *= sc * sc;   // undo tan normalization once

    // full 64-lane butterfly sum
    float v = tot;
    v += lxor<1>(v);
    v += lxor<2>(v);
    v += lxor<4>(v);
    v += lxor<8>(v);
    v += lxor<16>(v);
    v += lxor<32>(v);
    const int w = tid >> 6;
    if ((tid & 63) == 0) red[w] = v;
    __syncthreads();
    // signs on stored index: q0 -> j bit 11 = w bit 2; q1 -> j bit 10 = w bit 1;
    // q2 -> j bits 11^9 = w bits 2^0
    if (tid < 3) {
        float acc = 0.0f;
        #pragma unroll
        for (int ww = 0; ww < 8; ++ww) {
            int par = (tid == 0) ? ((ww >> 2) & 1)
                    : (tid == 1) ? ((ww >> 1) & 1)
                    :              (((ww >> 2) ^ ww) & 1);
            acc += par ? -red[ww] : red[ww];
        }
        out[b * 3 + tid] = acc;
    }
}

extern "C" void kernel_launch(void* const* d_in, const int* in_sizes, int n_in,
                              void* d_out, int out_size, void* d_ws, size_t ws_size,
                              hipStream_t stream) {
    (void)in_sizes; (void)n_in; (void)out_size; (void)d_ws; (void)ws_size;
    const float* x      = (const float*)d_in[0];   // [256,12] f32
    const float* thetas = (const float*)d_in[1];   // [6,12]   f32
    float* out          = (float*)d_out;           // [256,3]  f32

    qnet_kernel<<<dim3(NBATCH), dim3(NT), 0, stream>>>(x, thetas, out);
}